// Round 2
// baseline (217.764 us; speedup 1.0000x reference)
//
#include <hip/hip_runtime.h>
#include <stdint.h>

#define BATCH 64
#define MDIM 512
#define NDIM 512
#define KDIM 256
#define BT 64        // tile (square) per block
#define BK 32
#define NKSTEP 8     // KDIM / BK
#define TPB 8        // tiles per batch per dim (512/64)
#define NTILES 64    // TPB*TPB
#define LDSW 40      // padded row width in shorts (32 data + 8 pad -> 80B stride)

typedef __attribute__((ext_vector_type(8))) short short8;
typedef __attribute__((ext_vector_type(4))) float f32x4;

// fp32 -> bf16 RNE bit trick (data finite/normal)
__device__ __forceinline__ uint32_t f2bfu(float f) {
  uint32_t u = __float_as_uint(f);
  u += 0x7FFFu + ((u >> 16) & 1u);
  return u >> 16;
}

__device__ __forceinline__ float waveRedSum(float v) {
  v += __shfl_xor(v, 32);
  v += __shfl_xor(v, 16);
  v += __shfl_xor(v, 8);
  v += __shfl_xor(v, 4);
  v += __shfl_xor(v, 2);
  v += __shfl_xor(v, 1);
  return v;
}

// One 64-thread block (single wave) = one 64x64 tile of one batch.
// No __syncthreads anywhere: single-wave LDS pipeline, vmcnt/lgkmcnt only.
__global__ __launch_bounds__(64, 2) void pot_gemm_reduce(
    const float* __restrict__ V, const float* __restrict__ A,
    float* __restrict__ part) {
  // XCD swizzle: XCD x (bid%8) gets consecutive lin -> batches 8x..8x+7,
  // so each batch's 64 tiles are co-resident on one XCD (1MB << 4MB L2).
  const int bid = blockIdx.x;
  const int lin = (bid & 7) * 512 + (bid >> 3);
  const int b   = lin >> 6;        // batch
  const int t   = lin & 63;        // tile
  const int tm  = t >> 3;          // V strip
  const int tn  = t & 7;           // A strip

  const int lane = threadIdx.x;    // 0..63
  const int q    = lane >> 2;      // 0..15 : row group
  const int s    = lane & 3;       // 0..3  : 32B segment within BK row-chunk

  __shared__ short As[2][BT][LDSW];
  __shared__ short Bs[2][BT][LDSW];
  __shared__ float nvs[BT];
  __shared__ float nas[BT];

  // Per step, thread stages rows q+16i (i=0..3), fp32 cols [s*8, s*8+8).
  const float* Vg = V + ((size_t)b * MDIM + (size_t)tm * BT + q) * KDIM + s * 8;
  const float* Ag = A + ((size_t)b * NDIM + (size_t)tn * BT + q) * KDIM + s * 8;

  float sqa[4] = {0.f, 0.f, 0.f, 0.f};
  float sqb[4] = {0.f, 0.f, 0.f, 0.f};
  f32x4 acc[4][4];
#pragma unroll
  for (int m = 0; m < 4; ++m)
#pragma unroll
    for (int n = 0; n < 4; ++n)
      acc[m][n] = (f32x4){0.f, 0.f, 0.f, 0.f};

  float4 ra[4][2], rb[4][2];

#define ISSUE(k)                                                              \
  {                                                                           \
    _Pragma("unroll")                                                         \
    for (int i = 0; i < 4; ++i) {                                             \
      const float4* pa = reinterpret_cast<const float4*>(Vg + ((size_t)i * 16) * KDIM + (k) * BK); \
      const float4* pb = reinterpret_cast<const float4*>(Ag + ((size_t)i * 16) * KDIM + (k) * BK); \
      ra[i][0] = pa[0]; ra[i][1] = pa[1];                                     \
      rb[i][0] = pb[0]; rb[i][1] = pb[1];                                     \
    }                                                                         \
  }

#define PK8(dst, f0, f1)                                                      \
  {                                                                           \
    dst[0] = (short)f2bfu((f0).x); dst[1] = (short)f2bfu((f0).y);             \
    dst[2] = (short)f2bfu((f0).z); dst[3] = (short)f2bfu((f0).w);             \
    dst[4] = (short)f2bfu((f1).x); dst[5] = (short)f2bfu((f1).y);             \
    dst[6] = (short)f2bfu((f1).z); dst[7] = (short)f2bfu((f1).w);             \
  }

#define SQ4(acc_, f) { acc_ += (f).x*(f).x + (f).y*(f).y + (f).z*(f).z + (f).w*(f).w; }

#define CVTW(buf)                                                             \
  {                                                                           \
    _Pragma("unroll")                                                         \
    for (int i = 0; i < 4; ++i) {                                             \
      short8 wa, wb;                                                          \
      PK8(wa, ra[i][0], ra[i][1]);                                            \
      PK8(wb, rb[i][0], rb[i][1]);                                            \
      SQ4(sqa[i], ra[i][0]); SQ4(sqa[i], ra[i][1]);                           \
      SQ4(sqb[i], rb[i][0]); SQ4(sqb[i], rb[i][1]);                           \
      *reinterpret_cast<short8*>(&As[buf][q + 16 * i][s * 8]) = wa;           \
      *reinterpret_cast<short8*>(&Bs[buf][q + 16 * i][s * 8]) = wb;           \
    }                                                                         \
  }

#define COMPUTE(buf)                                                          \
  {                                                                           \
    short8 af[4], bf[4];                                                      \
    const int fr   = lane & 15;                                               \
    const int koff = (lane >> 4) * 8;                                         \
    _Pragma("unroll")                                                         \
    for (int m = 0; m < 4; ++m)                                               \
      af[m] = *reinterpret_cast<const short8*>(&As[buf][m * 16 + fr][koff]);  \
    _Pragma("unroll")                                                         \
    for (int n = 0; n < 4; ++n)                                               \
      bf[n] = *reinterpret_cast<const short8*>(&Bs[buf][n * 16 + fr][koff]);  \
    _Pragma("unroll")                                                         \
    for (int m = 0; m < 4; ++m)                                               \
      _Pragma("unroll")                                                       \
      for (int n = 0; n < 4; ++n)                                             \
        acc[m][n] = __builtin_amdgcn_mfma_f32_16x16x32_bf16(                  \
            af[m], bf[n], acc[m][n], 0, 0, 0);                                \
  }

  // software pipeline: regs hold k+1 while LDS buf holds k
  ISSUE(0);
  CVTW(0);
  ISSUE(1);
#pragma unroll
  for (int k = 0; k < NKSTEP; ++k) {
    COMPUTE(k & 1);
    if (k + 1 < NKSTEP) {
      CVTW((k + 1) & 1);              // consumes ISSUE(k+1) regs
      if (k + 2 < NKSTEP) ISSUE(k + 2);
    }
  }

  // 0.5*||row||^2 : reduce sq over the 4-lane segment group, lane s==0 writes
  {
#pragma unroll
    for (int i = 0; i < 4; ++i) {
      float va = sqa[i];
      va += __shfl_xor(va, 1); va += __shfl_xor(va, 2);
      float vb = sqb[i];
      vb += __shfl_xor(vb, 1); vb += __shfl_xor(vb, 2);
      if (s == 0) { nvs[q + 16 * i] = 0.5f * va; nas[q + 16 * i] = 0.5f * vb; }
    }
  }

  // epilogue: C = hnv + hna - dot ; T = exp(-C/1000); 4 scalar reductions
  float s0p = 0.f, ctp = 0.f, rsp = 0.f, csp = 0.f;
  const int rbase = (lane >> 4) * 4;
  const int cbase = lane & 15;
#pragma unroll
  for (int m = 0; m < 4; ++m) {
#pragma unroll
    for (int n = 0; n < 4; ++n) {
#pragma unroll
      for (int r = 0; r < 4; ++r) {
        const int lr = rbase + m * 16 + r;
        const int lc = cbase + n * 16;
        float Cv = nvs[lr] + nas[lc] - acc[m][n][r];
        float T = __expf(Cv * -1.0e-3f);
        s0p += T;
        ctp += Cv * T;
        rsp += (tm == 0 && lr == 0) ? T : 0.f;
        csp += (tn == 0 && lc == 0) ? T : 0.f;
      }
    }
  }

  s0p = waveRedSum(s0p);
  ctp = waveRedSum(ctp);
  rsp = waveRedSum(rsp);
  csp = waveRedSum(csp);
  if (lane == 0) {
    float* p = part + ((size_t)(b * NTILES + t)) * 4;
    p[0] = s0p; p[1] = ctp; p[2] = rsp; p[3] = csp;
  }
}

// One wave; thread b handles batch b: tree-reduce tile partials (deterministic),
// 10-iter scalar recurrence, mean over batches.
__global__ __launch_bounds__(64) void pot_finalize(
    const float* __restrict__ part, float* __restrict__ out) {
  const int b = threadIdx.x;  // 0..63
  float S0 = 0.f, CT = 0.f, RS = 0.f, CS = 0.f;
#pragma unroll
  for (int t = 0; t < NTILES; ++t) {
    const float* p = part + ((size_t)(b * NTILES + t)) * 4;
    S0 += p[0]; CT += p[1]; RS += p[2]; CS += p[3];
  }
  const float a0 = 1.0f / (float)MDIM;
  const float b0 = 1.0f / (float)NDIM;
  const float s  = (float)MDIM;  // min(m, n)
  float c = s / S0;
#pragma unroll
  for (int i = 0; i < 10; ++i) {
    float ka = fminf(a0 / (c * RS), 1.0f);
    float kb = fminf(b0 / (ka * c * CS), 1.0f);
    c = s * ka * kb / S0;
  }
  float D = c * CT;
  D = waveRedSum(D);
  if (b == 0) out[0] = D * (1.0f / (float)BATCH);
}

extern "C" void kernel_launch(void* const* d_in, const int* in_sizes, int n_in,
                              void* d_out, int out_size, void* d_ws, size_t ws_size,
                              hipStream_t stream) {
  const float* V = (const float*)d_in[0];   // v_emb [64,512,256] f32
  const float* A = (const float*)d_in[1];   // a_emb [64,512,256] f32
  float* out = (float*)d_out;               // 1 float
  float* part = (float*)d_ws;               // [64][64][4] f32 partials (64 KiB)

  pot_gemm_reduce<<<dim3(BATCH * NTILES), 64, 0, stream>>>(V, A, part);
  pot_finalize<<<1, 64, 0, stream>>>(part, out);
}

// Round 3
// 37.474 us; speedup vs baseline: 5.8111x; 5.8111x over previous
//
#include <hip/hip_runtime.h>
#include <stdint.h>

#define BATCH 64
#define MDIM 512
#define NDIM 512
#define KDIM 256
#define BM 128
#define BN 128
#define BK 32
#define NKSTEP 8    // KDIM / BK
#define NTILES 16   // (512/128)^2
#define LDSW 40     // padded row width in bf16 (32 data + 8 pad -> 80B stride)

typedef __attribute__((ext_vector_type(8))) short short8;
typedef __attribute__((ext_vector_type(4))) float f32x4;

// fp32 -> bf16 RNE bit trick (data finite/normal)
__device__ __forceinline__ short f2bf(float f) {
  uint32_t u = __float_as_uint(f);
  u += 0x7FFFu + ((u >> 16) & 1u);
  return (short)(u >> 16);
}

__device__ __forceinline__ float waveRedSum(float v) {
  v += __shfl_xor(v, 32);
  v += __shfl_xor(v, 16);
  v += __shfl_xor(v, 8);
  v += __shfl_xor(v, 4);
  v += __shfl_xor(v, 2);
  v += __shfl_xor(v, 1);
  return v;
}

// 512 threads = 8 waves; block = 128x128 tile of one batch's cost matrix.
// Wave grid 2x4, wave tile 64x32 -> acc only 8 frags (32 VGPR) per thread.
__global__ __launch_bounds__(512, 4) void pot_gemm_reduce(
    const float* __restrict__ V, const float* __restrict__ A,
    float* __restrict__ part) {
  // XCD swizzle: XCD (bid&7) gets a contiguous 128-block chunk (8 batches).
  const int bid = blockIdx.x;
  const int lin = (bid & 7) * 128 + (bid >> 3);
  const int b   = lin >> 4;        // batch
  const int t   = lin & 15;        // tile within batch
  const int tm  = t >> 2;
  const int tn  = t & 3;

  const int tid  = threadIdx.x;    // 0..511
  const int w    = tid >> 6;       // wave 0..7
  const int lane = tid & 63;
  const int wr   = w >> 2;         // 0..1 : 64-row strip
  const int wc   = w & 3;          // 0..3 : 32-col strip
  const int srow = tid >> 2;       // 0..127 staging row
  const int sseg = tid & 3;        // 0..3  staging 8-float segment

  __shared__ short As[2][BM][LDSW];
  __shared__ short Bs[2][BN][LDSW];
  __shared__ float nvs[BM];
  __shared__ float nas[BN];
  __shared__ float red[8][4];

  const float* Vg = V + ((size_t)b * MDIM + (size_t)tm * BM + srow) * KDIM + sseg * 8;
  const float* Ag = A + ((size_t)b * NDIM + (size_t)tn * BN + srow) * KDIM + sseg * 8;

  float sqa = 0.f, sqb = 0.f;
  f32x4 acc[4][2];
#pragma unroll
  for (int m = 0; m < 4; ++m)
#pragma unroll
    for (int n = 0; n < 2; ++n)
      acc[m][n] = (f32x4){0.f, 0.f, 0.f, 0.f};

  float4 ra0, ra1, rb0, rb1;   // only 16 regs of staging state

#define ISSUE(k)                                                              \
  {                                                                           \
    const float4* pa = reinterpret_cast<const float4*>(Vg + (k) * BK);        \
    const float4* pb = reinterpret_cast<const float4*>(Ag + (k) * BK);        \
    ra0 = pa[0]; ra1 = pa[1];                                                 \
    rb0 = pb[0]; rb1 = pb[1];                                                 \
  }

#define PK8(dst, f0, f1)                                                      \
  {                                                                           \
    dst[0] = f2bf((f0).x); dst[1] = f2bf((f0).y);                             \
    dst[2] = f2bf((f0).z); dst[3] = f2bf((f0).w);                             \
    dst[4] = f2bf((f1).x); dst[5] = f2bf((f1).y);                             \
    dst[6] = f2bf((f1).z); dst[7] = f2bf((f1).w);                             \
  }

#define SQ4(s_, f) { s_ += (f).x*(f).x + (f).y*(f).y + (f).z*(f).z + (f).w*(f).w; }

#define WRITE(buf)                                                            \
  {                                                                           \
    short8 wa, wb;                                                            \
    PK8(wa, ra0, ra1);                                                        \
    PK8(wb, rb0, rb1);                                                        \
    SQ4(sqa, ra0); SQ4(sqa, ra1);                                             \
    SQ4(sqb, rb0); SQ4(sqb, rb1);                                             \
    *reinterpret_cast<short8*>(&As[buf][srow][sseg * 8]) = wa;                \
    *reinterpret_cast<short8*>(&Bs[buf][srow][sseg * 8]) = wb;                \
  }

#define COMPUTE(buf)                                                          \
  {                                                                           \
    short8 af[4], bf[2];                                                      \
    const int fr   = lane & 15;                                               \
    const int koff = (lane >> 4) * 8;                                         \
    _Pragma("unroll")                                                         \
    for (int m = 0; m < 4; ++m)                                               \
      af[m] = *reinterpret_cast<const short8*>(                               \
          &As[buf][wr * 64 + m * 16 + fr][koff]);                             \
    _Pragma("unroll")                                                         \
    for (int n = 0; n < 2; ++n)                                               \
      bf[n] = *reinterpret_cast<const short8*>(                               \
          &Bs[buf][wc * 32 + n * 16 + fr][koff]);                             \
    _Pragma("unroll")                                                         \
    for (int m = 0; m < 4; ++m)                                               \
      _Pragma("unroll")                                                       \
      for (int n = 0; n < 2; ++n)                                             \
        acc[m][n] = __builtin_amdgcn_mfma_f32_16x16x32_bf16(                  \
            af[m], bf[n], acc[m][n], 0, 0, 0);                                \
  }

  // prologue
  ISSUE(0);
  WRITE(0);
  __syncthreads();

#pragma unroll
  for (int k = 0; k < NKSTEP; ++k) {
    if (k + 1 < NKSTEP) ISSUE(k + 1);    // loads in flight over the MFMAs
    COMPUTE(k & 1);
    if (k + 1 < NKSTEP) WRITE((k + 1) & 1);  // cvt+ds_write after compute
    __syncthreads();
  }

  // fp32 half-norms: reduce over the 4 segment lanes of each row
  {
    float va = sqa;
    va += __shfl_xor(va, 1); va += __shfl_xor(va, 2);
    float vb = sqb;
    vb += __shfl_xor(vb, 1); vb += __shfl_xor(vb, 2);
    if (sseg == 0) { nvs[srow] = 0.5f * va; nas[srow] = 0.5f * vb; }
  }
  __syncthreads();

  // epilogue: C = hnv + hna - dot ; T = exp(-C/1000); 4 scalar reductions
  float s0p = 0.f, ctp = 0.f, rsp = 0.f, csp = 0.f;
  const int rbase = wr * 64 + (lane >> 4) * 4;
  const int cbase = wc * 32 + (lane & 15);
#pragma unroll
  for (int m = 0; m < 4; ++m) {
#pragma unroll
    for (int n = 0; n < 2; ++n) {
#pragma unroll
      for (int r = 0; r < 4; ++r) {
        const int lr = rbase + m * 16 + r;
        const int lc = cbase + n * 16;
        float Cv = nvs[lr] + nas[lc] - acc[m][n][r];
        float T = __expf(Cv * -1.0e-3f);
        s0p += T;
        ctp += Cv * T;
        rsp += (tm == 0 && lr == 0) ? T : 0.f;
        csp += (tn == 0 && lc == 0) ? T : 0.f;
      }
    }
  }

  s0p = waveRedSum(s0p);
  ctp = waveRedSum(ctp);
  rsp = waveRedSum(rsp);
  csp = waveRedSum(csp);
  if (lane == 0) { red[w][0] = s0p; red[w][1] = ctp; red[w][2] = rsp; red[w][3] = csp; }
  __syncthreads();
  if (tid == 0) {
    float s0 = 0.f, ct = 0.f, rs = 0.f, cs = 0.f;
#pragma unroll
    for (int i = 0; i < 8; ++i) {
      s0 += red[i][0]; ct += red[i][1]; rs += red[i][2]; cs += red[i][3];
    }
    float* p = part + ((size_t)(b * NTILES + t)) * 4;
    p[0] = s0; p[1] = ct; p[2] = rs; p[3] = cs;
  }
}

// One wave; thread b handles batch b: deterministic tile reduce + 10-iter
// scalar recurrence + batch mean.
__global__ __launch_bounds__(64) void pot_finalize(
    const float* __restrict__ part, float* __restrict__ out) {
  const int b = threadIdx.x;  // 0..63
  float S0 = 0.f, CT = 0.f, RS = 0.f, CS = 0.f;
#pragma unroll
  for (int t = 0; t < NTILES; ++t) {
    const float* p = part + ((size_t)(b * NTILES + t)) * 4;
    S0 += p[0]; CT += p[1]; RS += p[2]; CS += p[3];
  }
  const float a0 = 1.0f / (float)MDIM;
  const float b0 = 1.0f / (float)NDIM;
  const float s  = (float)MDIM;  // min(m, n)
  float c = s / S0;
#pragma unroll
  for (int i = 0; i < 10; ++i) {
    float ka = fminf(a0 / (c * RS), 1.0f);
    float kb = fminf(b0 / (ka * c * CS), 1.0f);
    c = s * ka * kb / S0;
  }
  float D = c * CT;
  D = waveRedSum(D);
  if (b == 0) out[0] = D * (1.0f / (float)BATCH);
}

extern "C" void kernel_launch(void* const* d_in, const int* in_sizes, int n_in,
                              void* d_out, int out_size, void* d_ws, size_t ws_size,
                              hipStream_t stream) {
  const float* V = (const float*)d_in[0];   // v_emb [64,512,256] f32
  const float* A = (const float*)d_in[1];   // a_emb [64,512,256] f32
  float* out = (float*)d_out;               // 1 float
  float* part = (float*)d_ws;               // [64][16][4] f32 partials

  pot_gemm_reduce<<<dim3(BATCH * NTILES), 512, 0, stream>>>(V, A, part);
  pot_finalize<<<1, 64, 0, stream>>>(part, out);
}

// Round 4
// 28.659 us; speedup vs baseline: 7.5985x; 1.3076x over previous
//
#include <hip/hip_runtime.h>
#include <stdint.h>

#define BATCH 64
#define MDIM 512
#define NDIM 512
#define KDIM 256
#define BM 128
#define BN 128
#define BK 32
#define NKSTEP 8    // KDIM / BK
#define NTILES 16   // (512/128)^2
#define LDSW 40     // 32 data + 8 pad shorts -> 80B row stride (16B-aligned)

typedef __attribute__((ext_vector_type(8))) short short8;
typedef __attribute__((ext_vector_type(4))) float f32x4;
typedef __attribute__((ext_vector_type(4))) unsigned int u32x4;

// HW packed f32->bf16 RNE (no builtin on gfx950; m240 — single instr)
__device__ __forceinline__ unsigned int cvt_pk(float lo, float hi) {
  unsigned int r;
  asm("v_cvt_pk_bf16_f32 %0, %1, %2" : "=v"(r) : "v"(lo), "v"(hi));
  return r;
}

// Raw barrier: waits LDS ops only; global loads stay in flight (counted vmcnt).
#define BARRIER()                                         \
  {                                                       \
    asm volatile("s_waitcnt lgkmcnt(0)" ::: "memory");    \
    __builtin_amdgcn_s_barrier();                         \
    asm volatile("" ::: "memory");                        \
  }

__device__ __forceinline__ float waveRedSum(float v) {
  v += __shfl_xor(v, 32);
  v += __shfl_xor(v, 16);
  v += __shfl_xor(v, 8);
  v += __shfl_xor(v, 4);
  v += __shfl_xor(v, 2);
  v += __shfl_xor(v, 1);
  return v;
}

// 512 threads = 8 waves; block = 128x128 tile. Wave tile 64x32 (acc 32 VGPR).
// 2-deep register prefetch + raw barriers: loads never drained in main loop.
__global__ __launch_bounds__(512, 4) void pot_gemm_reduce(
    const float* __restrict__ V, const float* __restrict__ A,
    float* __restrict__ part) {
  const int bid = blockIdx.x;
  const int lin = (bid & 7) * 128 + (bid >> 3);   // XCD swizzle (1024%8==0)
  const int b   = lin >> 4;
  const int t   = lin & 15;
  const int tm  = t >> 2;
  const int tn  = t & 3;

  const int tid  = threadIdx.x;
  const int w    = tid >> 6;
  const int lane = tid & 63;
  const int wr   = w >> 2;         // 0..1 : 64-row strip
  const int wc   = w & 3;          // 0..3 : 32-col strip
  const int srow = tid >> 2;       // staging row 0..127
  const int sseg = tid & 3;        // staging 8-float segment

  // Exactly 40 KiB -> 4 blocks/CU. Norms & cross-wave scalars live in row pads.
  __shared__ short As[2][BM][LDSW];
  __shared__ short Bs[2][BN][LDSW];

  const float* Vg = V + ((size_t)b * MDIM + (size_t)tm * BM + srow) * KDIM + sseg * 8;
  const float* Ag = A + ((size_t)b * NDIM + (size_t)tn * BN + srow) * KDIM + sseg * 8;

  float sqa = 0.f, sqb = 0.f;
  f32x4 acc[4][2];
#pragma unroll
  for (int m = 0; m < 4; ++m)
#pragma unroll
    for (int n = 0; n < 2; ++n)
      acc[m][n] = (f32x4){0.f, 0.f, 0.f, 0.f};

  float4 ra[2][2], rb[2][2];   // 2 prefetch slots x 8 floats per matrix

#define ISSUE(k, slot)                                                        \
  {                                                                           \
    const float4* pa = reinterpret_cast<const float4*>(Vg + (k) * BK);        \
    const float4* pb = reinterpret_cast<const float4*>(Ag + (k) * BK);        \
    ra[slot][0] = pa[0]; ra[slot][1] = pa[1];                                 \
    rb[slot][0] = pb[0]; rb[slot][1] = pb[1];                                 \
  }

#define SQ4(s_, f) { s_ += (f).x*(f).x + (f).y*(f).y + (f).z*(f).z + (f).w*(f).w; }

#define WRITE(buf, slot)                                                      \
  {                                                                           \
    u32x4 wa, wb;                                                             \
    wa[0] = cvt_pk(ra[slot][0].x, ra[slot][0].y);                             \
    wa[1] = cvt_pk(ra[slot][0].z, ra[slot][0].w);                             \
    wa[2] = cvt_pk(ra[slot][1].x, ra[slot][1].y);                             \
    wa[3] = cvt_pk(ra[slot][1].z, ra[slot][1].w);                             \
    wb[0] = cvt_pk(rb[slot][0].x, rb[slot][0].y);                             \
    wb[1] = cvt_pk(rb[slot][0].z, rb[slot][0].w);                             \
    wb[2] = cvt_pk(rb[slot][1].x, rb[slot][1].y);                             \
    wb[3] = cvt_pk(rb[slot][1].z, rb[slot][1].w);                             \
    SQ4(sqa, ra[slot][0]); SQ4(sqa, ra[slot][1]);                             \
    SQ4(sqb, rb[slot][0]); SQ4(sqb, rb[slot][1]);                             \
    *reinterpret_cast<u32x4*>(&As[buf][srow][sseg * 8]) = wa;                 \
    *reinterpret_cast<u32x4*>(&Bs[buf][srow][sseg * 8]) = wb;                 \
  }

#define COMPUTE(buf)                                                          \
  {                                                                           \
    short8 af[4], bf[2];                                                      \
    const int fr   = lane & 15;                                               \
    const int koff = (lane >> 4) * 8;                                         \
    _Pragma("unroll")                                                         \
    for (int m = 0; m < 4; ++m)                                               \
      af[m] = *reinterpret_cast<const short8*>(                               \
          &As[buf][wr * 64 + m * 16 + fr][koff]);                             \
    _Pragma("unroll")                                                         \
    for (int n = 0; n < 2; ++n)                                               \
      bf[n] = *reinterpret_cast<const short8*>(                               \
          &Bs[buf][wc * 32 + n * 16 + fr][koff]);                             \
    _Pragma("unroll")                                                         \
    for (int m = 0; m < 4; ++m)                                               \
      _Pragma("unroll")                                                       \
      for (int n = 0; n < 2; ++n)                                             \
        acc[m][n] = __builtin_amdgcn_mfma_f32_16x16x32_bf16(                  \
            af[m], bf[n], acc[m][n], 0, 0, 0);                                \
  }

  // prologue: slots 0,1 in flight; buf0 staged
  ISSUE(0, 0);
  ISSUE(1, 1);
  WRITE(0, 0);          // compiler emits counted vmcnt(4) for slot-0 regs
  BARRIER();

#pragma unroll
  for (int k = 0; k < NKSTEP; ++k) {
    if (k + 2 < NKSTEP) ISSUE(k + 2, k & 1);      // refill slot just freed
    COMPUTE(k & 1);
    if (k + 1 < NKSTEP) WRITE((k + 1) & 1, (k + 1) & 1);
    BARRIER();          // raw: slot-(k+2) loads stay in flight across it
  }

  // half-norms 0.5*||row||^2 into the row pads of buffer 0 (disjoint from frags)
  {
    float va = sqa;
    va += __shfl_xor(va, 1); va += __shfl_xor(va, 2);
    float vb = sqb;
    vb += __shfl_xor(vb, 1); vb += __shfl_xor(vb, 2);
    if (sseg == 0) {
      *reinterpret_cast<float*>(&As[0][srow][32]) = 0.5f * va;
      *reinterpret_cast<float*>(&Bs[0][srow][32]) = 0.5f * vb;
    }
  }
  BARRIER();

  // epilogue: C = hnv + hna - dot ; T = exp(-C/1000); 4 scalar reductions
  float s0p = 0.f, ctp = 0.f, rsp = 0.f, csp = 0.f;
  const int rbase = wr * 64 + (lane >> 4) * 4;
  const int cbase = wc * 32 + (lane & 15);
#pragma unroll
  for (int m = 0; m < 4; ++m) {
#pragma unroll
    for (int n = 0; n < 2; ++n) {
#pragma unroll
      for (int r = 0; r < 4; ++r) {
        const int lr = rbase + m * 16 + r;
        const int lc = cbase + n * 16;
        float hn = *reinterpret_cast<const float*>(&As[0][lr][32]) +
                   *reinterpret_cast<const float*>(&Bs[0][lc][32]);
        float Cv = hn - acc[m][n][r];
        float T = __expf(Cv * -1.0e-3f);
        s0p += T;
        ctp += Cv * T;
        rsp += (tm == 0 && lr == 0) ? T : 0.f;
        csp += (tn == 0 && lc == 0) ? T : 0.f;
      }
    }
  }

  s0p = waveRedSum(s0p);
  ctp = waveRedSum(ctp);
  rsp = waveRedSum(rsp);
  csp = waveRedSum(csp);
  if (lane == 0) {
    // per-wave partials into Bs[1] row pads (f32x4 fits the 16B pad exactly)
    *reinterpret_cast<f32x4*>(&Bs[1][w][32]) = (f32x4){s0p, ctp, rsp, csp};
  }
  BARRIER();
  if (tid == 0) {
    float s0 = 0.f, ct = 0.f, rs = 0.f, cs = 0.f;
#pragma unroll
    for (int i = 0; i < 8; ++i) {
      f32x4 v = *reinterpret_cast<const f32x4*>(&Bs[1][i][32]);
      s0 += v[0]; ct += v[1]; rs += v[2]; cs += v[3];
    }
    float* p = part + ((size_t)(b * NTILES + t)) * 4;
    p[0] = s0; p[1] = ct; p[2] = rs; p[3] = cs;
  }
}

// One wave; thread b = batch b: deterministic tile reduce + 10-iter scalar
// recurrence + batch mean.
__global__ __launch_bounds__(64) void pot_finalize(
    const float* __restrict__ part, float* __restrict__ out) {
  const int b = threadIdx.x;
  float S0 = 0.f, CT = 0.f, RS = 0.f, CS = 0.f;
#pragma unroll
  for (int t = 0; t < NTILES; ++t) {
    const float* p = part + ((size_t)(b * NTILES + t)) * 4;
    S0 += p[0]; CT += p[1]; RS += p[2]; CS += p[3];
  }
  const float a0 = 1.0f / (float)MDIM;
  const float b0 = 1.0f / (float)NDIM;
  const float s  = (float)MDIM;
  float c = s / S0;
#pragma unroll
  for (int i = 0; i < 10; ++i) {
    float ka = fminf(a0 / (c * RS), 1.0f);
    float kb = fminf(b0 / (ka * c * CS), 1.0f);
    c = s * ka * kb / S0;
  }
  float D = c * CT;
  D = waveRedSum(D);
  if (b == 0) out[0] = D * (1.0f / (float)BATCH);
}

extern "C" void kernel_launch(void* const* d_in, const int* in_sizes, int n_in,
                              void* d_out, int out_size, void* d_ws, size_t ws_size,
                              hipStream_t stream) {
  const float* V = (const float*)d_in[0];   // v_emb [64,512,256] f32
  const float* A = (const float*)d_in[1];   // a_emb [64,512,256] f32
  float* out = (float*)d_out;
  float* part = (float*)d_ws;               // [64][16][4] f32 partials

  pot_gemm_reduce<<<dim3(BATCH * NTILES), 512, 0, stream>>>(V, A, part);
  pot_finalize<<<1, 64, 0, stream>>>(part, out);
}